// Round 2
// baseline (133.191 us; speedup 1.0000x reference)
//
#include <hip/hip_runtime.h>
#include <hip/hip_bf16.h>

#define NEGC (-1e8f)

__device__ __forceinline__ float lrelu(float x) { return x >= 0.f ? x : 0.2f * x; }

// Shared edge-logit computation. MUST be bit-identical between the stats pass
// and the output pass: the neg-mask multiplies e by -1e8, so a 1-ulp
// association difference in e becomes ~±50 in the logit and exp() explodes.
// Single fixed association: e = ss + soj, where soj = s_other[j] + b_att
// (precomputed identically in both kernels).
__device__ __forceinline__ void edge_pq(float ss, float soj, bool same,
                                        float& p, float& q) {
    float e = ss + soj;
    float pin = same ? e : e * NEGC;
    float nin = same ? e * NEGC : e;
    p = lrelu(pin);
    q = lrelu(nin);
}

// ---------------- Kernel 1: u1[d] = sum_k W[k,d]*w_att[k]; u2 with w_att[128+k];
//                  c[0]=dot(b_emb,w_att[:128]); c[1]=dot(b_emb,w_att[128:])
__global__ void prep_kernel(const float* __restrict__ W_emb,
                            const float* __restrict__ b_emb,
                            const float* __restrict__ w_att,
                            float* __restrict__ u1, float* __restrict__ u2,
                            float* __restrict__ c) {
    int k = threadIdx.x;  // 128 threads
    float a1 = 0.f, a2 = 0.f;
    for (int d = 0; d < 128; ++d) {
        float w = W_emb[d * 128 + k];
        a1 += w * w_att[d];
        a2 += w * w_att[128 + d];
    }
    u1[k] = a1;
    u2[k] = a2;

    __shared__ float r1[128], r2[128];
    r1[k] = b_emb[k] * w_att[k];
    r2[k] = b_emb[k] * w_att[128 + k];
    __syncthreads();
    for (int s = 64; s > 0; s >>= 1) {
        if (k < s) { r1[k] += r1[k + s]; r2[k] += r2[k + s]; }
        __syncthreads();
    }
    if (k == 0) { c[0] = r1[0]; c[1] = r2[0]; }
}

// ---------------- Kernel 2: per-row scores
__global__ void score_kernel(const float* __restrict__ node,
                             const float* __restrict__ u1,
                             const float* __restrict__ u2,
                             const float* __restrict__ c,
                             float* __restrict__ s_other,
                             float* __restrict__ s_self) {
    int i = blockIdx.x * blockDim.x + threadIdx.x;  // 1024 total
    float a1 = 0.f, a2 = 0.f;
    const float* row = node + (size_t)i * 128;
#pragma unroll 4
    for (int k = 0; k < 128; ++k) {
        float x = row[k];
        a1 += x * u1[k];
        a2 += x * u2[k];
    }
    s_other[i] = a1 + c[0];
    s_self[i]  = a2 + c[1];
}

__device__ __forceinline__ float block_bcast_reduce(float v, bool do_max, float* lds, int t) {
    // wave64 butterfly
    for (int off = 32; off > 0; off >>= 1) {
        float o = __shfl_xor(v, off, 64);
        v = do_max ? fmaxf(v, o) : (v + o);
    }
    int wave = t >> 6;
    if ((t & 63) == 0) lds[wave] = v;
    __syncthreads();
    if (t == 0) {
        float m = lds[0];
        for (int w = 1; w < 4; ++w) m = do_max ? fmaxf(m, lds[w]) : (m + lds[w]);
        lds[0] = m;
    }
    __syncthreads();
    float r = lds[0];
    __syncthreads();
    return r;
}

// ---------------- Kernel 3: per-column (axis-0) softmax stats. One block (256 thr) per column.
__global__ void col_stats_kernel(const float* __restrict__ s_self,
                                 const float* __restrict__ s_other,
                                 const int* __restrict__ group,
                                 const float* __restrict__ b_att,
                                 float* __restrict__ cmp, float* __restrict__ csp,
                                 float* __restrict__ cmn, float* __restrict__ csn,
                                 int n) {
    int j = blockIdx.x;
    int t = threadIdx.x;  // 256
    float soj = s_other[j] + b_att[0];
    int gj = group[j];

    float pv[4], nv[4];
    float pmax = -3.4e38f, nmax = -3.4e38f;
#pragma unroll
    for (int k = 0; k < 4; ++k) {
        int i = t + k * 256;
        bool same = (group[i] == gj);
        float p, q;
        edge_pq(s_self[i], soj, same, p, q);
        pv[k] = p; nv[k] = q;
        pmax = fmaxf(pmax, p);
        nmax = fmaxf(nmax, q);
    }
    __shared__ float lds[4];
    pmax = block_bcast_reduce(pmax, true, lds, t);
    nmax = block_bcast_reduce(nmax, true, lds, t);

    float psum = 0.f, nsum = 0.f;
#pragma unroll
    for (int k = 0; k < 4; ++k) {
        psum += expf(pv[k] - pmax);
        nsum += expf(nv[k] - nmax);
    }
    psum = block_bcast_reduce(psum, false, lds, t);
    nsum = block_bcast_reduce(nsum, false, lds, t);

    if (t == 0) {
        cmp[j] = pmax; csp[j] = psum;
        cmn[j] = nmax; csn[j] = nsum;
    }
}

// ---------------- Kernel 4: out[i,:] = sum_j (pa+na)[i,j] * relu(node[j,:])
// Block: 256 threads, BI=8 rows. j tiled by 64 with A-tile in LDS.
#define BI 8
__global__ void out_kernel(const float* __restrict__ node,
                           const float* __restrict__ s_self,
                           const float* __restrict__ s_other,
                           const int* __restrict__ group,
                           const float* __restrict__ b_att,
                           const float* __restrict__ cmp, const float* __restrict__ csp,
                           const float* __restrict__ cmn, const float* __restrict__ csn,
                           float* __restrict__ out, int n) {
    int i0 = blockIdx.x * BI;
    int t = threadIdx.x;          // 256
    int d = t & 127;
    int half = t >> 7;            // 0/1

    __shared__ float sA[BI][64];
    __shared__ float ss_l[BI];
    __shared__ int   g_l[BI];
    if (t < BI) { ss_l[t] = s_self[i0 + t]; g_l[t] = group[i0 + t]; }
    __syncthreads();

    float ba = b_att[0];
    float acc[4] = {0.f, 0.f, 0.f, 0.f};

    for (int j0 = 0; j0 < n; j0 += 64) {
        // fill A tile: 512 entries, 2 per thread
#pragma unroll
        for (int e = 0; e < 2; ++e) {
            int idx = t + e * 256;     // 0..511
            int r = idx >> 6;          // row 0..7
            int jj = idx & 63;
            int j = j0 + jj;
            float soj = s_other[j] + ba;          // identical association to col_stats
            bool same = (g_l[r] == group[j]);
            float p, q;
            edge_pq(ss_l[r], soj, same, p, q);
            float a = expf(p - cmp[j]) / csp[j] + expf(q - cmn[j]) / csn[j];
            sA[r][jj] = a;
        }
        __syncthreads();

        for (int jj = 0; jj < 64; ++jj) {
            int j = j0 + jj;
            float x = node[(size_t)j * 128 + d];
            float rn = x > 0.f ? x : 0.f;
#pragma unroll
            for (int r = 0; r < 4; ++r) {
                acc[r] += sA[half * 4 + r][jj] * rn;
            }
        }
        __syncthreads();
    }

#pragma unroll
    for (int r = 0; r < 4; ++r) {
        out[(size_t)(i0 + half * 4 + r) * 128 + d] = acc[r];
    }
}

extern "C" void kernel_launch(void* const* d_in, const int* in_sizes, int n_in,
                              void* d_out, int out_size, void* d_ws, size_t ws_size,
                              hipStream_t stream) {
    const float* node  = (const float*)d_in[0];
    const int*   group = (const int*)d_in[1];
    const float* W_emb = (const float*)d_in[2];
    const float* b_emb = (const float*)d_in[3];
    const float* w_att = (const float*)d_in[4];
    const float* b_att = (const float*)d_in[5];
    float* out = (float*)d_out;

    const int n = in_sizes[1];   // 1024

    float* w = (float*)d_ws;
    float* u1      = w;            // 128
    float* u2      = w + 128;      // 128
    float* c       = w + 256;      // 2
    float* s_other = w + 512;      // n
    float* s_self  = w + 512 + n;  // n
    float* cmp     = w + 512 + 2 * n;
    float* csp     = cmp + n;
    float* cmn     = csp + n;
    float* csn     = cmn + n;

    prep_kernel<<<1, 128, 0, stream>>>(W_emb, b_emb, w_att, u1, u2, c);
    score_kernel<<<n / 256, 256, 0, stream>>>(node, u1, u2, c, s_other, s_self);
    col_stats_kernel<<<n, 256, 0, stream>>>(s_self, s_other, group, b_att,
                                            cmp, csp, cmn, csn, n);
    out_kernel<<<n / BI, 256, 0, stream>>>(node, s_self, s_other, group, b_att,
                                           cmp, csp, cmn, csn, out, n);
}

// Round 3
// 32.569 us; speedup vs baseline: 4.0895x; 4.0895x over previous
//
#include <hip/hip_runtime.h>
#include <hip/hip_bf16.h>

#define NEGC (-1e8f)

__device__ __forceinline__ float lrelu(float x) { return x >= 0.f ? x : 0.2f * x; }

// Shared edge-logit computation. MUST be bit-identical between the stats pass
// and the output pass: the neg-mask multiplies e by -1e8, so a 1-ulp
// association difference becomes ~±50 in the logit and exp() explodes.
// Fixed association: e = ss + soj, soj = s_other[j] + b_att (identical in both).
__device__ __forceinline__ void edge_pq(float ss, float soj, bool same,
                                        float& p, float& q) {
    float e = ss + soj;
    float pin = same ? e : e * NEGC;
    float nin = same ? e * NEGC : e;
    p = lrelu(pin);
    q = lrelu(nin);
}

// ---------------- Kernel 1: u1[k] = sum_d W[d,k]*w_att[d]; u2 with w_att[128+d];
// c[0]=dot(b_emb,w_att[:128]); c[1]=dot(b_emb,w_att[128:])
__global__ void prep_kernel(const float* __restrict__ W_emb,
                            const float* __restrict__ b_emb,
                            const float* __restrict__ w_att,
                            float* __restrict__ u1, float* __restrict__ u2,
                            float* __restrict__ c) {
    int k = threadIdx.x;  // 128
    float a1 = 0.f, a2 = 0.f;
    for (int d = 0; d < 128; ++d) {
        float w = W_emb[d * 128 + k];
        a1 += w * w_att[d];
        a2 += w * w_att[128 + d];
    }
    u1[k] = a1;
    u2[k] = a2;

    __shared__ float r1[128], r2[128];
    r1[k] = b_emb[k] * w_att[k];
    r2[k] = b_emb[k] * w_att[128 + k];
    __syncthreads();
    for (int s = 64; s > 0; s >>= 1) {
        if (k < s) { r1[k] += r1[k + s]; r2[k] += r2[k + s]; }
        __syncthreads();
    }
    if (k == 0) { c[0] = r1[0]; c[1] = r2[0]; }
}

// ---------------- Kernel 2: per-row scores (float4 loads)
__global__ void score_kernel(const float* __restrict__ node,
                             const float* __restrict__ u1,
                             const float* __restrict__ u2,
                             const float* __restrict__ c,
                             float* __restrict__ s_other,
                             float* __restrict__ s_self) {
    int i = blockIdx.x * blockDim.x + threadIdx.x;
    const float4* row4 = (const float4*)(node + (size_t)i * 128);
    const float4* u14 = (const float4*)u1;
    const float4* u24 = (const float4*)u2;
    float a1 = 0.f, a2 = 0.f;
#pragma unroll 8
    for (int k = 0; k < 32; ++k) {
        float4 x = row4[k];
        float4 v1 = u14[k];
        float4 v2 = u24[k];
        a1 += x.x * v1.x + x.y * v1.y + x.z * v1.z + x.w * v1.w;
        a2 += x.x * v2.x + x.y * v2.y + x.z * v2.z + x.w * v2.w;
    }
    s_other[i] = a1 + c[0];
    s_self[i]  = a2 + c[1];
}

// ---------------- Kernel 3: per-column softmax stats, one wave per column.
// 4 columns/block (256 thr), register logits, shfl butterflies, no barriers.
// Stores max and RECIPROCAL of sum. Assumes n == 1024.
__global__ void col_stats_kernel(const float* __restrict__ s_self,
                                 const float* __restrict__ s_other,
                                 const int* __restrict__ group,
                                 const float* __restrict__ b_att,
                                 float* __restrict__ cmp, float* __restrict__ icsp,
                                 float* __restrict__ cmn, float* __restrict__ icsn,
                                 int n) {
    int j = blockIdx.x * 4 + (threadIdx.x >> 6);
    int lane = threadIdx.x & 63;
    float soj = s_other[j] + b_att[0];
    int gj = group[j];

    float pv[16], nv[16];
    float pmax = -3.4e38f, nmax = -3.4e38f;
#pragma unroll
    for (int k = 0; k < 16; ++k) {
        int i = lane + k * 64;
        float p, q;
        edge_pq(s_self[i], soj, group[i] == gj, p, q);
        pv[k] = p; nv[k] = q;
        pmax = fmaxf(pmax, p);
        nmax = fmaxf(nmax, q);
    }
#pragma unroll
    for (int off = 32; off > 0; off >>= 1) {
        pmax = fmaxf(pmax, __shfl_xor(pmax, off, 64));
        nmax = fmaxf(nmax, __shfl_xor(nmax, off, 64));
    }
    float psum = 0.f, nsum = 0.f;
#pragma unroll
    for (int k = 0; k < 16; ++k) {
        psum += expf(pv[k] - pmax);
        nsum += expf(nv[k] - nmax);
    }
#pragma unroll
    for (int off = 32; off > 0; off >>= 1) {
        psum += __shfl_xor(psum, off, 64);
        nsum += __shfl_xor(nsum, off, 64);
    }
    if (lane == 0) {
        cmp[j] = pmax; icsp[j] = 1.f / psum;
        cmn[j] = nmax; icsn[j] = 1.f / nsum;
    }
}

// ---------------- Kernel 4: out[i,:] = sum_j (pa+na)[i,j] * relu(node[j,:])
// BI=4 rows/block -> 256 blocks x 256 thr. Whole A rows filled once in LDS
// (no barriers in main loop). 8 j-groups of 32 lanes; each group owns
// j = g, g+8, ... and loads a FULL relu(node[j,:]) row as 32 coalesced float4.
// Final cross-group reduce through LDS.
#define BI 4
__global__ __launch_bounds__(256) void out_kernel(
        const float* __restrict__ node,
        const float* __restrict__ s_self,
        const float* __restrict__ s_other,
        const int* __restrict__ group,
        const float* __restrict__ b_att,
        const float* __restrict__ cmp, const float* __restrict__ icsp,
        const float* __restrict__ cmn, const float* __restrict__ icsn,
        float* __restrict__ out, int n) {
    int i0 = blockIdx.x * BI;
    int t = threadIdx.x;  // 256

    __shared__ float sA[BI][1024];   // 16 KB, reused as reduce buffer
    __shared__ float ss_l[BI];
    __shared__ int   g_l[BI];
    if (t < BI) { ss_l[t] = s_self[i0 + t]; g_l[t] = group[i0 + t]; }
    __syncthreads();

    float ba = b_att[0];
#pragma unroll
    for (int r = 0; r < BI; ++r) {
        float ss = ss_l[r];
        int gr = g_l[r];
        for (int j = t; j < n; j += 256) {
            float soj = s_other[j] + ba;        // identical association to col_stats
            float p, q;
            edge_pq(ss, soj, group[j] == gr, p, q);
            sA[r][j] = expf(p - cmp[j]) * icsp[j] + expf(q - cmn[j]) * icsn[j];
        }
    }
    __syncthreads();

    int lane = t & 31;   // float4 index within a 128-d row
    int g = t >> 5;      // j-group 0..7
    const float4* nf4 = (const float4*)node;

    float4 acc[BI];
#pragma unroll
    for (int r = 0; r < BI; ++r) acc[r] = make_float4(0.f, 0.f, 0.f, 0.f);

#pragma unroll 4
    for (int j = g; j < n; j += 8) {
        float4 x = nf4[(size_t)j * 32 + lane];
        float4 rn;
        rn.x = fmaxf(x.x, 0.f); rn.y = fmaxf(x.y, 0.f);
        rn.z = fmaxf(x.z, 0.f); rn.w = fmaxf(x.w, 0.f);
#pragma unroll
        for (int r = 0; r < BI; ++r) {
            float a = sA[r][j];
            acc[r].x += a * rn.x; acc[r].y += a * rn.y;
            acc[r].z += a * rn.z; acc[r].w += a * rn.w;
        }
    }

    __syncthreads();  // done reading sA; reuse as reduce buffer
    float4* red = (float4*)sA;  // layout: red[g*BI*32 + r*32 + lane], 8*BI*32 float4 = 16 KB
#pragma unroll
    for (int r = 0; r < BI; ++r) red[g * (BI * 32) + r * 32 + lane] = acc[r];
    __syncthreads();

    // 512 outputs (BI rows x 128 d); 2 per thread
#pragma unroll
    for (int s = 0; s < 2; ++s) {
        int o = t + s * 256;          // 0..511
        int r = o >> 7;               // row 0..3
        int d = o & 127;
        float sum = 0.f;
        float* rf = (float*)sA;
#pragma unroll
        for (int gg = 0; gg < 8; ++gg)
            sum += rf[(gg * (BI * 32) + r * 32) * 4 + d];
        out[(size_t)(i0 + r) * 128 + d] = sum;
    }
}

extern "C" void kernel_launch(void* const* d_in, const int* in_sizes, int n_in,
                              void* d_out, int out_size, void* d_ws, size_t ws_size,
                              hipStream_t stream) {
    const float* node  = (const float*)d_in[0];
    const int*   group = (const int*)d_in[1];
    const float* W_emb = (const float*)d_in[2];
    const float* b_emb = (const float*)d_in[3];
    const float* w_att = (const float*)d_in[4];
    const float* b_att = (const float*)d_in[5];
    float* out = (float*)d_out;

    const int n = in_sizes[1];   // 1024

    float* w = (float*)d_ws;
    float* u1      = w;            // 128
    float* u2      = w + 128;      // 128
    float* c       = w + 256;      // 2
    float* s_other = w + 512;      // n
    float* s_self  = w + 512 + n;  // n
    float* cmp     = w + 512 + 2 * n;
    float* icsp    = cmp + n;
    float* cmn     = icsp + n;
    float* icsn    = cmn + n;

    prep_kernel<<<1, 128, 0, stream>>>(W_emb, b_emb, w_att, u1, u2, c);
    score_kernel<<<n / 256, 256, 0, stream>>>(node, u1, u2, c, s_other, s_self);
    col_stats_kernel<<<n / 4, 256, 0, stream>>>(s_self, s_other, group, b_att,
                                                cmp, icsp, cmn, icsn, n);
    out_kernel<<<n / BI, 256, 0, stream>>>(node, s_self, s_other, group, b_att,
                                           cmp, icsp, cmn, icsn, out, n);
}

// Round 4
// 25.244 us; speedup vs baseline: 5.2760x; 1.2901x over previous
//
#include <hip/hip_runtime.h>
#include <hip/hip_bf16.h>

#define NEGC (-1e8f)

__device__ __forceinline__ float lrelu(float x) { return x >= 0.f ? x : 0.2f * x; }

// Shared edge-logit computation. MUST be bit-identical between the stats pass
// and the output pass: the neg-mask multiplies e by -1e8, so a 1-ulp
// association difference becomes ~±50 in the logit and exp() explodes.
// Fixed association: e = ss + soj, soj = s_other[j] + b_att (identical in both).
// The exp() evaluations themselves need NOT be bit-identical across kernels:
// only the logits feed the 1e8 amplification; exp(0)=1 exactly either way.
__device__ __forceinline__ void edge_pq(float ss, float soj, bool same,
                                        float& p, float& q) {
    float e = ss + soj;
    float pin = same ? e : e * NEGC;
    float nin = same ? e * NEGC : e;
    p = lrelu(pin);
    q = lrelu(nin);
}

// ---------------- Kernel 1: fused prep + score. 8 blocks x 128 thr.
// Phase 1 (redundant per block, tiny): u1[k]=sum_e W[e,k]*w1[e], u2 likewise,
// c1=dot(b_emb,w1), c2=dot(b_emb,w2) -> u in LDS, c via shfl butterfly.
// Phase 2: each thread computes one row's s_other/s_self.
__global__ __launch_bounds__(128) void k1_prep_score(
        const float* __restrict__ node,
        const float* __restrict__ W_emb,
        const float* __restrict__ b_emb,
        const float* __restrict__ w_att,
        float* __restrict__ s_other,
        float* __restrict__ s_self) {
    int lane = threadIdx.x;  // 0..127
    float a1 = 0.f, a2 = 0.f;
    for (int e = 0; e < 128; ++e) {
        float w = W_emb[e * 128 + lane];
        a1 += w * w_att[e];
        a2 += w * w_att[128 + e];
    }
    __shared__ float u1[128], u2[128];
    u1[lane] = a1;
    u2[lane] = a2;

    float c1 = b_emb[lane] * w_att[lane];
    float c2 = b_emb[lane] * w_att[128 + lane];
#pragma unroll
    for (int off = 32; off > 0; off >>= 1) {
        c1 += __shfl_xor(c1, off, 64);
        c2 += __shfl_xor(c2, off, 64);
    }
    __shared__ float cw[4];
    if ((lane & 63) == 0) { cw[(lane >> 6) * 2] = c1; cw[(lane >> 6) * 2 + 1] = c2; }
    __syncthreads();
    c1 = cw[0] + cw[2];
    c2 = cw[1] + cw[3];

    int i = blockIdx.x * 128 + lane;
    const float4* row4 = (const float4*)(node + (size_t)i * 128);
    const float4* u14 = (const float4*)u1;
    const float4* u24 = (const float4*)u2;
    float b1 = 0.f, b2 = 0.f;
#pragma unroll 8
    for (int k = 0; k < 32; ++k) {
        float4 x = row4[k];
        float4 v1 = u14[k];
        float4 v2 = u24[k];
        b1 += x.x * v1.x + x.y * v1.y + x.z * v1.z + x.w * v1.w;
        b2 += x.x * v2.x + x.y * v2.y + x.z * v2.z + x.w * v2.w;
    }
    s_other[i] = b1 + c1;
    s_self[i]  = b2 + c2;
}

// ---------------- Kernel 2: per-column softmax stats, one wave per column.
// 4 columns/block (256 thr), register logits, shfl butterflies, no barriers.
// Stores max and RECIPROCAL of sum. Assumes n == 1024.
__global__ __launch_bounds__(256) void k2_col_stats(
        const float* __restrict__ s_self,
        const float* __restrict__ s_other,
        const int* __restrict__ group,
        const float* __restrict__ b_att,
        float* __restrict__ cmp, float* __restrict__ icsp,
        float* __restrict__ cmn, float* __restrict__ icsn) {
    int j = blockIdx.x * 4 + (threadIdx.x >> 6);
    int lane = threadIdx.x & 63;
    float soj = s_other[j] + b_att[0];
    int gj = group[j];

    float pv[16], nv[16];
    float pmax = -3.4e38f, nmax = -3.4e38f;
#pragma unroll
    for (int k = 0; k < 16; ++k) {
        int i = lane + k * 64;
        float p, q;
        edge_pq(s_self[i], soj, group[i] == gj, p, q);
        pv[k] = p; nv[k] = q;
        pmax = fmaxf(pmax, p);
        nmax = fmaxf(nmax, q);
    }
#pragma unroll
    for (int off = 32; off > 0; off >>= 1) {
        pmax = fmaxf(pmax, __shfl_xor(pmax, off, 64));
        nmax = fmaxf(nmax, __shfl_xor(nmax, off, 64));
    }
    float psum = 0.f, nsum = 0.f;
#pragma unroll
    for (int k = 0; k < 16; ++k) {
        psum += __expf(pv[k] - pmax);
        nsum += __expf(nv[k] - nmax);
    }
#pragma unroll
    for (int off = 32; off > 0; off >>= 1) {
        psum += __shfl_xor(psum, off, 64);
        nsum += __shfl_xor(nsum, off, 64);
    }
    if (lane == 0) {
        cmp[j] = pmax; icsp[j] = 1.f / psum;
        cmn[j] = nmax; icsn[j] = 1.f / nsum;
    }
}

// ---------------- Kernel 3: out[i,:] = sum_j (pa+na)[i,j] * relu(node[j,:])
// BI=4 rows/block, 256 blocks x 512 thr (2 waves/SIMD). A rows filled once in
// 16 KB LDS; 16 j-groups of 32 lanes each own j == g (mod 16): 64-iter main
// loop, unroll 8 (8 float4 loads in flight). 32 KB LDS reused for the
// cross-group reduce.
#define BI 4
__global__ __launch_bounds__(512) void k3_out(
        const float* __restrict__ node,
        const float* __restrict__ s_self,
        const float* __restrict__ s_other,
        const int* __restrict__ group,
        const float* __restrict__ b_att,
        const float* __restrict__ cmp, const float* __restrict__ icsp,
        const float* __restrict__ cmn, const float* __restrict__ icsn,
        float* __restrict__ out) {
    int t = threadIdx.x;       // 0..511
    int i0 = blockIdx.x * BI;

    __shared__ float buf[8192];   // 32 KB; first 4096 floats = sA[4][1024]
    __shared__ float ss_l[BI];
    __shared__ int   g_l[BI];
    if (t < BI) { ss_l[t] = s_self[i0 + t]; g_l[t] = group[i0 + t]; }
    __syncthreads();

    float ba = b_att[0];
#pragma unroll
    for (int e = 0; e < 8; ++e) {
        int idx = t + e * 512;        // 0..4095
        int r = idx >> 10;            // row 0..3
        int j = idx & 1023;
        float soj = s_other[j] + ba;  // identical association to k2_col_stats
        float p, q;
        edge_pq(ss_l[r], soj, group[j] == g_l[r], p, q);
        buf[r * 1024 + j] = __expf(p - cmp[j]) * icsp[j]
                          + __expf(q - cmn[j]) * icsn[j];
    }
    __syncthreads();

    int lane = t & 31;   // float4 index within a 128-d row
    int g = t >> 5;      // j-group 0..15
    const float4* nf4 = (const float4*)node;

    float4 acc[BI];
#pragma unroll
    for (int r = 0; r < BI; ++r) acc[r] = make_float4(0.f, 0.f, 0.f, 0.f);

#pragma unroll 8
    for (int j = g; j < 1024; j += 16) {
        float4 x = nf4[(size_t)j * 32 + lane];
        float4 rn;
        rn.x = fmaxf(x.x, 0.f); rn.y = fmaxf(x.y, 0.f);
        rn.z = fmaxf(x.z, 0.f); rn.w = fmaxf(x.w, 0.f);
#pragma unroll
        for (int r = 0; r < BI; ++r) {
            float a = buf[r * 1024 + j];
            acc[r].x += a * rn.x; acc[r].y += a * rn.y;
            acc[r].z += a * rn.z; acc[r].w += a * rn.w;
        }
    }

    __syncthreads();  // done reading sA; reuse buf as reduce buffer
    float4* red = (float4*)buf;   // red[g*128 + r*32 + lane], 2048 float4 = 32 KB
#pragma unroll
    for (int r = 0; r < BI; ++r) red[g * 128 + r * 32 + lane] = acc[r];
    __syncthreads();

    // 512 outputs (BI rows x 128 d); 1 per thread, contiguous store
    int r = t >> 7;
    int d = t & 127;
    float sum = 0.f;
#pragma unroll
    for (int gg = 0; gg < 16; ++gg)
        sum += buf[gg * 512 + r * 128 + d];
    out[(size_t)(i0 + r) * 128 + d] = sum;
}

extern "C" void kernel_launch(void* const* d_in, const int* in_sizes, int n_in,
                              void* d_out, int out_size, void* d_ws, size_t ws_size,
                              hipStream_t stream) {
    const float* node  = (const float*)d_in[0];
    const int*   group = (const int*)d_in[1];
    const float* W_emb = (const float*)d_in[2];
    const float* b_emb = (const float*)d_in[3];
    const float* w_att = (const float*)d_in[4];
    const float* b_att = (const float*)d_in[5];
    float* out = (float*)d_out;

    const int n = in_sizes[1];   // 1024

    float* w = (float*)d_ws;
    float* s_other = w;            // n
    float* s_self  = w + n;        // n
    float* cmp     = w + 2 * n;
    float* icsp    = w + 3 * n;
    float* cmn     = w + 4 * n;
    float* icsn    = w + 5 * n;

    k1_prep_score<<<n / 128, 128, 0, stream>>>(node, W_emb, b_emb, w_att,
                                               s_other, s_self);
    k2_col_stats<<<n / 4, 256, 0, stream>>>(s_self, s_other, group, b_att,
                                            cmp, icsp, cmn, icsn);
    k3_out<<<n / BI, 512, 0, stream>>>(node, s_self, s_other, group, b_att,
                                       cmp, icsp, cmn, icsn, out);
}